// Round 1
// baseline (360.860 us; speedup 1.0000x reference)
//
#include <hip/hip_runtime.h>

#define T_LEN 32768
#define ADIM  512
#define NDEC  1024
#define KTAPS 31

// workspace float offsets
#define WS_BASE 0        // 512   : dec_proj[a] + conv-bias proj
#define WS_G    512      // 15872 : G[k][a] = sum_c conv_w[c,k]*W_att[a,c]
#define WS_SARR 16384    // 32768 : s[t] = 2*(e[t]+mask[t])
#define WS_BMAX 49152    // 512   : per-block online max
#define WS_BSUM 49664    // 512   : per-block online sumexp
#define WS_MZ   50176    // 2     : global (M, Z)
#define WS_SSUM 50178    // 1     : sum of clipped u
#define WS_U    50432    // 32768 : u[t]

__device__ __forceinline__ float fast_tanh(float x) {
    // tanh(x) = 1 - 2/(exp(2x)+1); v_exp + v_rcp, ~1e-7 abs err — fine vs 3.5e-4 threshold
    float e = __expf(2.0f * x);
    return 1.0f - 2.0f * __builtin_amdgcn_rcpf(e + 1.0f);
}

// ---------------- K0: dec_proj+bias -> base[512]; G[31][512]; zero-init ----------------
__global__ __launch_bounds__(256) void k0_prep(
        const float* __restrict__ dec_z, const float* __restrict__ conv_w,
        const float* __restrict__ conv_b, const float* __restrict__ W_att,
        const float* __restrict__ W_dec, float* __restrict__ ws, float* __restrict__ out) {
    int b = blockIdx.x, tid = threadIdx.x;
    int lane = tid & 63, wave = tid >> 6;
    if (b < 64) {
        // blocks 0..63: 8 a's each, wave handles 2 a's (64-lane dot over 1024)
        for (int s = 0; s < 2; ++s) {
            int a = b * 8 + wave * 2 + s;
            float sum = 0.f;
            #pragma unroll
            for (int i = 0; i < 16; ++i)
                sum += W_dec[a * NDEC + i * 64 + lane] * dec_z[i * 64 + lane];
            #pragma unroll
            for (int off = 32; off > 0; off >>= 1) sum += __shfl_xor(sum, off);
            if (lane == 0) {
                float bias = 0.f;
                for (int c = 0; c < 32; ++c) bias += conv_b[c] * W_att[a * 32 + c];
                ws[WS_BASE + a] = sum + bias;
            }
        }
    } else if (b < 64 + KTAPS) {
        int k = b - 64;
        for (int r = 0; r < 2; ++r) {
            int a = tid + r * 256;
            float g = 0.f;
            #pragma unroll
            for (int c = 0; c < 32; ++c) g += conv_w[c * KTAPS + k] * W_att[a * 32 + c];
            ws[WS_G + k * ADIM + a] = g;
        }
    } else {
        // block 95: zero c-accumulator region of d_out and the S atomic slot
        out[tid] = 0.f;
        out[tid + 256] = 0.f;
        if (tid == 0) ws[WS_SSUM] = 0.f;
    }
}

// ---------------- K1: s[t] = 2*(e[t]+mask[t]) + per-block online (max,sumexp) ----------
// block = 256 thr (4 waves), 64 t's per block; wave: 16 t's in 2 batches of 8;
// lane owns a in {4l..4l+3, 256+4l..256+4l+3}; G from LDS (2x ds_read_b128/k, reused x8 t)
__global__ __launch_bounds__(256, 2) void k1_energy(
        const float* __restrict__ att_prev, const float* __restrict__ pre,
        const float* __restrict__ mask, const float* __restrict__ W_g,
        const float* __restrict__ b_g, float* __restrict__ ws) {
    __shared__ float Gs[KTAPS * ADIM];   // 63488 B
    __shared__ float ap_s[96];
    __shared__ float wm[4], wz[4];
    int tid = threadIdx.x, lane = tid & 63, wave = tid >> 6;
    int t0 = blockIdx.x * 64;

    // stage G (15872 floats = 3968 float4)
    const float4* Gsrc = (const float4*)(ws + WS_G);
    float4* Gdst = (float4*)Gs;
    #pragma unroll
    for (int i = 0; i < 16; ++i) {
        int idx = tid + i * 256;
        if (idx < 3968) Gdst[idx] = Gsrc[idx];
    }
    // stage att_prev window [t0-15, t0+78], zero-padded
    if (tid < 94) {
        int g = t0 - 15 + tid;
        ap_s[tid] = (g >= 0 && g < T_LEN) ? att_prev[g] : 0.f;
    }
    __syncthreads();

    int aA = 4 * lane, aB = 256 + 4 * lane;
    float4 baseA = *(const float4*)(ws + WS_BASE + aA);
    float4 baseB = *(const float4*)(ws + WS_BASE + aB);
    float4 wgA = *(const float4*)(W_g + aA);
    float4 wgB = *(const float4*)(W_g + aB);
    float bg = b_g[0];

    float m_run = -1e30f, z_run = 0.f;

    for (int b8 = 0; b8 < 2; ++b8) {
        int tb_local = wave * 16 + b8 * 8;
        int tb = t0 + tb_local;
        float ap_r[38];
        #pragma unroll
        for (int i = 0; i < 38; ++i) ap_r[i] = ap_s[tb_local + i];

        float acc[8][8];
        #pragma unroll
        for (int j = 0; j < 8; ++j) {
            acc[j][0] = baseA.x; acc[j][1] = baseA.y; acc[j][2] = baseA.z; acc[j][3] = baseA.w;
            acc[j][4] = baseB.x; acc[j][5] = baseB.y; acc[j][6] = baseB.z; acc[j][7] = baseB.w;
        }
        #pragma unroll
        for (int k = 0; k < KTAPS; ++k) {
            float4 gA = *(const float4*)(&Gs[k * ADIM + aA]);
            float4 gB = *(const float4*)(&Gs[k * ADIM + aB]);
            #pragma unroll
            for (int j = 0; j < 8; ++j) {
                float apv = ap_r[j + k];
                acc[j][0] = fmaf(apv, gA.x, acc[j][0]);
                acc[j][1] = fmaf(apv, gA.y, acc[j][1]);
                acc[j][2] = fmaf(apv, gA.z, acc[j][2]);
                acc[j][3] = fmaf(apv, gA.w, acc[j][3]);
                acc[j][4] = fmaf(apv, gB.x, acc[j][4]);
                acc[j][5] = fmaf(apv, gB.y, acc[j][5]);
                acc[j][6] = fmaf(apv, gB.z, acc[j][6]);
                acc[j][7] = fmaf(apv, gB.w, acc[j][7]);
            }
        }
        #pragma unroll
        for (int j = 0; j < 8; ++j) {
            int t = tb + j;
            float4 pA = *(const float4*)(pre + (size_t)t * ADIM + aA);
            float4 pB = *(const float4*)(pre + (size_t)t * ADIM + aB);
            float ps = 0.f;
            ps = fmaf(fast_tanh(pA.x + acc[j][0]), wgA.x, ps);
            ps = fmaf(fast_tanh(pA.y + acc[j][1]), wgA.y, ps);
            ps = fmaf(fast_tanh(pA.z + acc[j][2]), wgA.z, ps);
            ps = fmaf(fast_tanh(pA.w + acc[j][3]), wgA.w, ps);
            ps = fmaf(fast_tanh(pB.x + acc[j][4]), wgB.x, ps);
            ps = fmaf(fast_tanh(pB.y + acc[j][5]), wgB.y, ps);
            ps = fmaf(fast_tanh(pB.z + acc[j][6]), wgB.z, ps);
            ps = fmaf(fast_tanh(pB.w + acc[j][7]), wgB.w, ps);
            #pragma unroll
            for (int off = 32; off > 0; off >>= 1) ps += __shfl_xor(ps, off);
            float sv = 2.0f * (ps + bg + mask[t]);
            float mn = fmaxf(m_run, sv);
            z_run = z_run * __expf(m_run - mn) + __expf(sv - mn);
            m_run = mn;
            if (lane == 0) ws[WS_SARR + t] = sv;
        }
    }
    if (lane == 0) { wm[wave] = m_run; wz[wave] = z_run; }
    __syncthreads();
    if (tid == 0) {
        float M = wm[0], Z = wz[0];
        #pragma unroll
        for (int w = 1; w < 4; ++w) {
            float mn = fmaxf(M, wm[w]);
            Z = Z * __expf(M - mn) + wz[w] * __expf(wm[w] - mn);
            M = mn;
        }
        ws[WS_BMAX + blockIdx.x] = M;
        ws[WS_BSUM + blockIdx.x] = Z;
    }
}

// ---------------- K2: combine 512 (max,sumexp) pairs -> M, Z --------------------------
__global__ __launch_bounds__(256) void k2_combine(float* __restrict__ ws) {
    __shared__ float sm[256], sz[256];
    int tid = threadIdx.x;
    float m1 = ws[WS_BMAX + tid],       z1 = ws[WS_BSUM + tid];
    float m2 = ws[WS_BMAX + tid + 256], z2 = ws[WS_BSUM + tid + 256];
    float M = fmaxf(m1, m2);
    float Z = z1 * __expf(m1 - M) + z2 * __expf(m2 - M);
    sm[tid] = M; sz[tid] = Z;
    __syncthreads();
    for (int s = 128; s > 0; s >>= 1) {
        if (tid < s) {
            float ma = sm[tid], mb = sm[tid + s];
            float mn = fmaxf(ma, mb);
            sz[tid] = sz[tid] * __expf(ma - mn) + sz[tid + s] * __expf(mb - mn);
            sm[tid] = mn;
        }
        __syncthreads();
    }
    if (tid == 0) { ws[WS_MZ] = sm[0]; ws[WS_MZ + 1] = sz[0]; }
}

// ---------------- K3: u[t] = clip((ap[t]+ap[t-1])*softmax, 1e-6); S = sum u ----------
__global__ __launch_bounds__(256) void k3_weights(
        const float* __restrict__ att_prev, float* __restrict__ ws) {
    int tid = threadIdx.x;
    int t = blockIdx.x * 256 + tid;
    float M = ws[WS_MZ];
    float invZ = 1.0f / ws[WS_MZ + 1];
    float pair = att_prev[t] + ((t > 0) ? att_prev[t - 1] : 0.f);
    float u = fmaxf(pair * __expf(ws[WS_SARR + t] - M) * invZ, 1e-6f);
    ws[WS_U + t] = u;
    float s = u;
    #pragma unroll
    for (int off = 32; off > 0; off >>= 1) s += __shfl_xor(s, off);
    __shared__ float wsum[4];
    int lane = tid & 63, wave = tid >> 6;
    if (lane == 0) wsum[wave] = s;
    __syncthreads();
    if (tid == 0) atomicAdd(&ws[WS_SSUM], wsum[0] + wsum[1] + wsum[2] + wsum[3]);
}

// ---------------- K4: w[t] = u/S -> d_out[512+t]; c = w^T enc_h -> d_out[0:512] -------
__global__ __launch_bounds__(256) void k4_context(
        const float* __restrict__ enc_h, const float* __restrict__ ws,
        float* __restrict__ out) {
    __shared__ float cbuf[512];
    int tid = threadIdx.x;
    int half = tid >> 7, l = tid & 127;
    int a4 = 4 * l;
    int t0 = blockIdx.x * 128 + half * 64;
    float invS = 1.0f / ws[WS_SSUM];
    float4 acc = make_float4(0.f, 0.f, 0.f, 0.f);
    for (int i = 0; i < 64; ++i) {
        int t = t0 + i;
        float wt = ws[WS_U + t] * invS;
        float4 e = *(const float4*)(enc_h + (size_t)t * ADIM + a4);
        acc.x = fmaf(wt, e.x, acc.x);
        acc.y = fmaf(wt, e.y, acc.y);
        acc.z = fmaf(wt, e.z, acc.z);
        acc.w = fmaf(wt, e.w, acc.w);
        if (l == 0) out[512 + t] = wt;
    }
    if (half == 1) *(float4*)&cbuf[a4] = acc;
    __syncthreads();
    if (half == 0) {
        float4 o = *(const float4*)&cbuf[a4];
        atomicAdd(&out[a4 + 0], acc.x + o.x);
        atomicAdd(&out[a4 + 1], acc.y + o.y);
        atomicAdd(&out[a4 + 2], acc.z + o.z);
        atomicAdd(&out[a4 + 3], acc.w + o.w);
    }
}

extern "C" void kernel_launch(void* const* d_in, const int* in_sizes, int n_in,
                              void* d_out, int out_size, void* d_ws, size_t ws_size,
                              hipStream_t stream) {
    const float* dec_z    = (const float*)d_in[0];
    const float* att_prev = (const float*)d_in[1];
    const float* pre      = (const float*)d_in[2];
    const float* enc_h    = (const float*)d_in[3];
    const float* mask     = (const float*)d_in[4];
    const float* conv_w   = (const float*)d_in[5];
    const float* conv_b   = (const float*)d_in[6];
    const float* W_att    = (const float*)d_in[7];
    const float* W_dec    = (const float*)d_in[8];
    const float* W_g      = (const float*)d_in[9];
    const float* b_g      = (const float*)d_in[10];
    float* out = (float*)d_out;
    float* ws  = (float*)d_ws;

    k0_prep   <<<96,  256, 0, stream>>>(dec_z, conv_w, conv_b, W_att, W_dec, ws, out);
    k1_energy <<<512, 256, 0, stream>>>(att_prev, pre, mask, W_g, b_g, ws);
    k2_combine<<<1,   256, 0, stream>>>(ws);
    k3_weights<<<128, 256, 0, stream>>>(att_prev, ws);
    k4_context<<<256, 256, 0, stream>>>(enc_h, ws, out);
}

// Round 2
// 235.350 us; speedup vs baseline: 1.5333x; 1.5333x over previous
//
#include <hip/hip_runtime.h>

#define T_LEN 32768
#define ADIM  512
#define NDEC  1024
#define KTAPS 31

// workspace float offsets
#define WS_BASE 0        // 512   : dec_proj[a] + conv-bias proj
#define WS_G    512      // 15872 : G[k][a] = sum_c conv_w[c,k]*W_att[a,c]
#define WS_SARR 16384    // 32768 : s[t] = 2*(e[t]+mask[t])
#define WS_BMAX 49152    // 512   : per-block online max
#define WS_BSUM 49664    // 512   : per-block online sumexp
#define WS_SSUM 50178    // 1     : sum of clipped u
#define WS_U    50432    // 32768 : u[t]

__device__ __forceinline__ float fast_tanh(float x) {
    // tanh(x) = 1 - 2/(exp(2x)+1); ~1e-7 abs err vs 3.5e-4 threshold
    float e = __expf(2.0f * x);
    return 1.0f - 2.0f * __builtin_amdgcn_rcpf(e + 1.0f);
}

__device__ __forceinline__ float uniform_f(float v) {
    // force wave-uniform value into an SGPR (readfirstlane)
    return __uint_as_float(__builtin_amdgcn_readfirstlane(__float_as_uint(v)));
}

// ---------------- K0: dec_proj+bias -> base[512]; G[31][512]; zero-init ----------------
__global__ __launch_bounds__(256) void k0_prep(
        const float* __restrict__ dec_z, const float* __restrict__ conv_w,
        const float* __restrict__ conv_b, const float* __restrict__ W_att,
        const float* __restrict__ W_dec, float* __restrict__ ws, float* __restrict__ out) {
    int b = blockIdx.x, tid = threadIdx.x;
    int lane = tid & 63, wave = tid >> 6;
    if (b < 64) {
        // blocks 0..63: 8 a's each, wave handles 2 a's (64-lane dot over 1024)
        for (int s = 0; s < 2; ++s) {
            int a = b * 8 + wave * 2 + s;
            float sum = 0.f;
            #pragma unroll
            for (int i = 0; i < 16; ++i)
                sum += W_dec[a * NDEC + i * 64 + lane] * dec_z[i * 64 + lane];
            #pragma unroll
            for (int off = 32; off > 0; off >>= 1) sum += __shfl_xor(sum, off);
            if (lane == 0) {
                float bias = 0.f;
                for (int c = 0; c < 32; ++c) bias += conv_b[c] * W_att[a * 32 + c];
                ws[WS_BASE + a] = sum + bias;
            }
        }
    } else if (b < 64 + KTAPS) {
        int k = b - 64;
        for (int r = 0; r < 2; ++r) {
            int a = tid + r * 256;
            float g = 0.f;
            #pragma unroll
            for (int c = 0; c < 32; ++c) g += conv_w[c * KTAPS + k] * W_att[a * 32 + c];
            ws[WS_G + k * ADIM + a] = g;
        }
    } else {
        // block 95: zero c-accumulator region of d_out and the S atomic slot
        out[tid] = 0.f;
        out[tid + 256] = 0.f;
        if (tid == 0) ws[WS_SSUM] = 0.f;
    }
}

// ---------------- K1: s[t]=2*(e[t]+mask[t]) + per-block online (max,sumexp) -----------
// 512 blocks x 64 t. Wave handles 16 t's in 2 batches of 8; within a batch the two
// 256-wide a-halves are processed sequentially (float4 acc[8] = 32 VGPR each).
// ap window lives in SGPRs (readfirstlane); pre[t] prefetched before the k-loop.
__global__ __launch_bounds__(256, 2) void k1_energy(
        const float* __restrict__ att_prev, const float* __restrict__ pre,
        const float* __restrict__ mask, const float* __restrict__ W_g,
        const float* __restrict__ b_g, float* __restrict__ ws) {
    __shared__ float Gs[KTAPS * ADIM];   // 63488 B
    __shared__ float ap_s[96];
    __shared__ float wm[4], wz[4];
    int tid = threadIdx.x, lane = tid & 63, wave = tid >> 6;
    int t0 = blockIdx.x * 64;

    // stage G (15872 floats = 3968 float4)
    const float4* Gsrc = (const float4*)(ws + WS_G);
    float4* Gdst = (float4*)Gs;
    #pragma unroll
    for (int i = 0; i < 16; ++i) {
        int idx = tid + i * 256;
        if (idx < 3968) Gdst[idx] = Gsrc[idx];
    }
    // stage att_prev window [t0-15, t0+78], zero-padded
    if (tid < 94) {
        int g = t0 - 15 + tid;
        ap_s[tid] = (g >= 0 && g < T_LEN) ? att_prev[g] : 0.f;
    }
    __syncthreads();

    float bg = b_g[0];
    float m_run = -1e30f, z_run = 0.f;

    #pragma unroll 1
    for (int b8 = 0; b8 < 2; ++b8) {
        int tb_local = wave * 16 + b8 * 8;
        int tb = t0 + tb_local;

        // wave-uniform ap window -> SGPRs (38 values, zero VGPR cost)
        float ap_u[38];
        #pragma unroll
        for (int i = 0; i < 38; ++i) ap_u[i] = uniform_f(ap_s[tb_local + i]);

        float ps[8];
        #pragma unroll
        for (int j = 0; j < 8; ++j) ps[j] = 0.f;

        #pragma unroll 1
        for (int half = 0; half < 2; ++half) {
            int aa = half * 256 + 4 * lane;
            float4 base = *(const float4*)(ws + WS_BASE + aa);
            float4 wg   = *(const float4*)(W_g + aa);

            // prefetch pre[t] for the 8 t's of this half (hidden under k-loop)
            float4 p[8];
            #pragma unroll
            for (int j = 0; j < 8; ++j)
                p[j] = *(const float4*)(pre + (size_t)(tb + j) * ADIM + aa);

            float4 acc[8];
            #pragma unroll
            for (int j = 0; j < 8; ++j) acc[j] = base;

            #pragma unroll
            for (int k = 0; k < KTAPS; ++k) {
                float4 g = *(const float4*)(&Gs[k * ADIM + aa]);
                #pragma unroll
                for (int j = 0; j < 8; ++j) {
                    float apv = ap_u[j + k];
                    acc[j].x = fmaf(apv, g.x, acc[j].x);
                    acc[j].y = fmaf(apv, g.y, acc[j].y);
                    acc[j].z = fmaf(apv, g.z, acc[j].z);
                    acc[j].w = fmaf(apv, g.w, acc[j].w);
                }
            }
            #pragma unroll
            for (int j = 0; j < 8; ++j) {
                float s = ps[j];
                s = fmaf(fast_tanh(p[j].x + acc[j].x), wg.x, s);
                s = fmaf(fast_tanh(p[j].y + acc[j].y), wg.y, s);
                s = fmaf(fast_tanh(p[j].z + acc[j].z), wg.z, s);
                s = fmaf(fast_tanh(p[j].w + acc[j].w), wg.w, s);
                ps[j] = s;
            }
        }
        #pragma unroll
        for (int j = 0; j < 8; ++j) {
            float e = ps[j];
            #pragma unroll
            for (int off = 32; off > 0; off >>= 1) e += __shfl_xor(e, off);
            int t = tb + j;
            float sv = 2.0f * (e + bg + mask[t]);
            float mn = fmaxf(m_run, sv);
            z_run = z_run * __expf(m_run - mn) + __expf(sv - mn);
            m_run = mn;
            if (lane == 0) ws[WS_SARR + t] = sv;
        }
    }
    if (lane == 0) { wm[wave] = m_run; wz[wave] = z_run; }
    __syncthreads();
    if (tid == 0) {
        float M = wm[0], Z = wz[0];
        #pragma unroll
        for (int w = 1; w < 4; ++w) {
            float mn = fmaxf(M, wm[w]);
            Z = Z * __expf(M - mn) + wz[w] * __expf(wm[w] - mn);
            M = mn;
        }
        ws[WS_BMAX + blockIdx.x] = M;
        ws[WS_BSUM + blockIdx.x] = Z;
    }
}

// ---------------- K2: per-block redundant (M,Z) combine; u[t]; atomic S ---------------
__global__ __launch_bounds__(256) void k2_weights(
        const float* __restrict__ att_prev, float* __restrict__ ws) {
    __shared__ float sm[256], sz[256];
    __shared__ float wsum[4];
    int tid = threadIdx.x;
    // combine the 512 (max,sumexp) pairs — redundantly per block (cheap, L2-hot)
    float m1 = ws[WS_BMAX + tid],       z1 = ws[WS_BSUM + tid];
    float m2 = ws[WS_BMAX + tid + 256], z2 = ws[WS_BSUM + tid + 256];
    float M = fmaxf(m1, m2);
    float Z = z1 * __expf(m1 - M) + z2 * __expf(m2 - M);
    sm[tid] = M; sz[tid] = Z;
    __syncthreads();
    for (int s = 128; s > 0; s >>= 1) {
        if (tid < s) {
            float ma = sm[tid], mb = sm[tid + s];
            float mn = fmaxf(ma, mb);
            sz[tid] = sz[tid] * __expf(ma - mn) + sz[tid + s] * __expf(mb - mn);
            sm[tid] = mn;
        }
        __syncthreads();
    }
    M = sm[0];
    float invZ = 1.0f / sz[0];
    int t = blockIdx.x * 256 + tid;
    float pair = att_prev[t] + ((t > 0) ? att_prev[t - 1] : 0.f);
    float u = fmaxf(pair * __expf(ws[WS_SARR + t] - M) * invZ, 1e-6f);
    ws[WS_U + t] = u;
    float s = u;
    #pragma unroll
    for (int off = 32; off > 0; off >>= 1) s += __shfl_xor(s, off);
    int lane = tid & 63, wave = tid >> 6;
    if (lane == 0) wsum[wave] = s;
    __syncthreads();
    if (tid == 0) atomicAdd(&ws[WS_SSUM], wsum[0] + wsum[1] + wsum[2] + wsum[3]);
}

// ---------------- K3: w[t] = u/S -> d_out[512+t]; c = w^T enc_h -> d_out[0:512] -------
// 512 blocks x 64 t; two 128-thread teams each cover 32 t's across all 512 a's.
__global__ __launch_bounds__(256) void k3_context(
        const float* __restrict__ enc_h, const float* __restrict__ ws,
        float* __restrict__ out) {
    __shared__ float cbuf[512];
    int tid = threadIdx.x;
    int half = tid >> 7, l = tid & 127;
    int a4 = 4 * l;
    int t0 = blockIdx.x * 64;
    float invS = 1.0f / ws[WS_SSUM];
    // coalesced w-write for this block's 64 t's
    if (tid < 64) out[512 + t0 + tid] = ws[WS_U + t0 + tid] * invS;
    int tbase = t0 + half * 32;
    float4 acc = make_float4(0.f, 0.f, 0.f, 0.f);
    #pragma unroll 4
    for (int i = 0; i < 32; ++i) {
        int t = tbase + i;
        float wt = ws[WS_U + t] * invS;
        float4 e = *(const float4*)(enc_h + (size_t)t * ADIM + a4);
        acc.x = fmaf(wt, e.x, acc.x);
        acc.y = fmaf(wt, e.y, acc.y);
        acc.z = fmaf(wt, e.z, acc.z);
        acc.w = fmaf(wt, e.w, acc.w);
    }
    if (half == 1) *(float4*)&cbuf[a4] = acc;
    __syncthreads();
    if (half == 0) {
        float4 o = *(const float4*)&cbuf[a4];
        atomicAdd(&out[a4 + 0], acc.x + o.x);
        atomicAdd(&out[a4 + 1], acc.y + o.y);
        atomicAdd(&out[a4 + 2], acc.z + o.z);
        atomicAdd(&out[a4 + 3], acc.w + o.w);
    }
}

extern "C" void kernel_launch(void* const* d_in, const int* in_sizes, int n_in,
                              void* d_out, int out_size, void* d_ws, size_t ws_size,
                              hipStream_t stream) {
    const float* dec_z    = (const float*)d_in[0];
    const float* att_prev = (const float*)d_in[1];
    const float* pre      = (const float*)d_in[2];
    const float* enc_h    = (const float*)d_in[3];
    const float* mask     = (const float*)d_in[4];
    const float* conv_w   = (const float*)d_in[5];
    const float* conv_b   = (const float*)d_in[6];
    const float* W_att    = (const float*)d_in[7];
    const float* W_dec    = (const float*)d_in[8];
    const float* W_g      = (const float*)d_in[9];
    const float* b_g      = (const float*)d_in[10];
    float* out = (float*)d_out;
    float* ws  = (float*)d_ws;

    k0_prep   <<<96,  256, 0, stream>>>(dec_z, conv_w, conv_b, W_att, W_dec, ws, out);
    k1_energy <<<512, 256, 0, stream>>>(att_prev, pre, mask, W_g, b_g, ws);
    k2_weights<<<128, 256, 0, stream>>>(att_prev, ws);
    k3_context<<<512, 256, 0, stream>>>(enc_h, ws, out);
}

// Round 4
// 190.279 us; speedup vs baseline: 1.8965x; 1.2369x over previous
//
#include <hip/hip_runtime.h>

#define T_LEN 32768
#define ADIM  512
#define NDEC  1024
#define KTAPS 31

// workspace float offsets
#define WS_BASE 0        // 512   : dec_proj[a] + conv-bias proj        (k0->k1)
#define WS_G    512      // 15872 : G[k][a] = sum_c conv_w[c,k]*W_att   (k0->k1)
#define WS_CREP 0        // 16384 : 32 replicated c-accumulators — ALIASES BASE+G,
                         //         zeroed by k2 (after k1 is done), used k3->k4
#define WS_SARR 16384    // 32768 : s[t] = 2*(e[t]+mask[t])
#define WS_BMAX 49152    // 512   : per-block online max
#define WS_BSUM 49664    // 512   : per-block online sumexp
#define WS_SSUM 50178    // 1     : sum of clipped u
#define WS_U    50432    // 32768 : u[t]

__device__ __forceinline__ float fast_tanh(float x) {
    // tanh(x) = 1 - 2/(exp(2x)+1); ~1e-7 abs err vs 3.5e-4 threshold
    float e = __expf(2.0f * x);
    return 1.0f - 2.0f * __builtin_amdgcn_rcpf(e + 1.0f);
}

__device__ __forceinline__ float uniform_f(float v) {
    return __uint_as_float(__builtin_amdgcn_readfirstlane(__float_as_uint(v)));
}

// ---------------- K0: dec_proj+bias -> base[512]; G[31][512] --------------------------
__global__ __launch_bounds__(256) void k0_prep(
        const float* __restrict__ dec_z, const float* __restrict__ conv_w,
        const float* __restrict__ conv_b, const float* __restrict__ W_att,
        const float* __restrict__ W_dec, float* __restrict__ ws) {
    int b = blockIdx.x, tid = threadIdx.x;
    int lane = tid & 63, wave = tid >> 6;
    if (b < 64) {
        // 8 a's per block, wave handles 2 (64-lane dot over 1024)
        for (int s = 0; s < 2; ++s) {
            int a = b * 8 + wave * 2 + s;
            float sum = 0.f;
            #pragma unroll
            for (int i = 0; i < 16; ++i)
                sum += W_dec[a * NDEC + i * 64 + lane] * dec_z[i * 64 + lane];
            #pragma unroll
            for (int off = 32; off > 0; off >>= 1) sum += __shfl_xor(sum, off);
            if (lane == 0) {
                float bias = 0.f;
                #pragma unroll
                for (int c = 0; c < 32; ++c) bias += conv_b[c] * W_att[a * 32 + c];
                ws[WS_BASE + a] = sum + bias;
            }
        }
    } else if (b < 64 + KTAPS) {
        int k = b - 64;
        for (int r = 0; r < 2; ++r) {
            int a = tid + r * 256;
            float g = 0.f;
            #pragma unroll
            for (int c = 0; c < 32; ++c) g += conv_w[c * KTAPS + k] * W_att[a * 32 + c];
            ws[WS_G + k * ADIM + a] = g;
        }
    } else {
        if (tid == 0) ws[WS_SSUM] = 0.f;
    }
}

// ---------------- K1: s[t]=2*(e[t]+mask[t]) + per-block online (max,sumexp) -----------
// 512 blocks x 512 thr (8 waves). Wave w owns t = t0+8w .. t0+8w+7; the two 256-wide
// a-halves processed sequentially (float4 acc[8] = 32 VGPR each). ap window in SGPRs.
__global__ __launch_bounds__(512, 4) void k1_energy(
        const float* __restrict__ att_prev, const float* __restrict__ pre,
        const float* __restrict__ mask, const float* __restrict__ W_g,
        const float* __restrict__ b_g, float* __restrict__ ws) {
    __shared__ float Gs[KTAPS * ADIM];   // 63488 B
    __shared__ float ap_s[96];
    __shared__ float wm[8], wz[8];
    int tid = threadIdx.x, lane = tid & 63, wave = tid >> 6;
    int t0 = blockIdx.x * 64;

    // stage G (15872 floats = 3968 float4)
    const float4* Gsrc = (const float4*)(ws + WS_G);
    float4* Gdst = (float4*)Gs;
    #pragma unroll
    for (int i = 0; i < 8; ++i) {
        int idx = tid + i * 512;
        if (idx < 3968) Gdst[idx] = Gsrc[idx];
    }
    if (tid < 94) {
        int g = t0 - 15 + tid;
        ap_s[tid] = (g >= 0 && g < T_LEN) ? att_prev[g] : 0.f;
    }
    __syncthreads();

    float bg = b_g[0];
    int tb_local = wave * 8;
    int tb = t0 + tb_local;

    // wave-uniform ap window -> SGPRs
    float ap_u[38];
    #pragma unroll
    for (int i = 0; i < 38; ++i) ap_u[i] = uniform_f(ap_s[tb_local + i]);

    float ps[8];
    #pragma unroll
    for (int j = 0; j < 8; ++j) ps[j] = 0.f;

    #pragma unroll 1
    for (int half = 0; half < 2; ++half) {
        int aa = half * 256 + 4 * lane;
        float4 base = *(const float4*)(ws + WS_BASE + aa);
        float4 wg   = *(const float4*)(W_g + aa);

        float4 p[8];
        #pragma unroll
        for (int j = 0; j < 8; ++j)
            p[j] = *(const float4*)(pre + (size_t)(tb + j) * ADIM + aa);

        float4 acc[8];
        #pragma unroll
        for (int j = 0; j < 8; ++j) acc[j] = base;

        #pragma unroll
        for (int k = 0; k < KTAPS; ++k) {
            float4 g = *(const float4*)(&Gs[k * ADIM + aa]);
            #pragma unroll
            for (int j = 0; j < 8; ++j) {
                float apv = ap_u[j + k];
                acc[j].x = fmaf(apv, g.x, acc[j].x);
                acc[j].y = fmaf(apv, g.y, acc[j].y);
                acc[j].z = fmaf(apv, g.z, acc[j].z);
                acc[j].w = fmaf(apv, g.w, acc[j].w);
            }
        }
        #pragma unroll
        for (int j = 0; j < 8; ++j) {
            float s = ps[j];
            s = fmaf(fast_tanh(p[j].x + acc[j].x), wg.x, s);
            s = fmaf(fast_tanh(p[j].y + acc[j].y), wg.y, s);
            s = fmaf(fast_tanh(p[j].z + acc[j].z), wg.z, s);
            s = fmaf(fast_tanh(p[j].w + acc[j].w), wg.w, s);
            ps[j] = s;
        }
    }

    float m_run = -1e30f, z_run = 0.f;
    #pragma unroll
    for (int j = 0; j < 8; ++j) {
        float e = ps[j];
        #pragma unroll
        for (int off = 32; off > 0; off >>= 1) e += __shfl_xor(e, off);
        int t = tb + j;
        float sv = 2.0f * (e + bg + mask[t]);
        float mn = fmaxf(m_run, sv);
        z_run = z_run * __expf(m_run - mn) + __expf(sv - mn);
        m_run = mn;
        if (lane == 0) ws[WS_SARR + t] = sv;
    }
    if (lane == 0) { wm[wave] = m_run; wz[wave] = z_run; }
    __syncthreads();
    if (tid == 0) {
        float M = wm[0], Z = wz[0];
        #pragma unroll
        for (int w = 1; w < 8; ++w) {
            float mn = fmaxf(M, wm[w]);
            Z = Z * __expf(M - mn) + wz[w] * __expf(wm[w] - mn);
            M = mn;
        }
        ws[WS_BMAX + blockIdx.x] = M;
        ws[WS_BSUM + blockIdx.x] = Z;
    }
}

// ---------------- K2: (M,Z) combine; u[t]; atomic S; zero c-replicas ------------------
__global__ __launch_bounds__(256) void k2_weights(
        const float* __restrict__ att_prev, float* __restrict__ ws) {
    __shared__ float sm[256], sz[256];
    __shared__ float wsum[4];
    int tid = threadIdx.x;
    // zero the 32 replicated c-accumulators (region aliases BASE+G — dead after k1):
    // 128 blocks x 128 floats = 16384 floats
    if (tid < 128) ws[WS_CREP + blockIdx.x * 128 + tid] = 0.f;

    float m1 = ws[WS_BMAX + tid],       z1 = ws[WS_BSUM + tid];
    float m2 = ws[WS_BMAX + tid + 256], z2 = ws[WS_BSUM + tid + 256];
    float M = fmaxf(m1, m2);
    float Z = z1 * __expf(m1 - M) + z2 * __expf(m2 - M);
    sm[tid] = M; sz[tid] = Z;
    __syncthreads();
    for (int s = 128; s > 0; s >>= 1) {
        if (tid < s) {
            float ma = sm[tid], mb = sm[tid + s];
            float mn = fmaxf(ma, mb);
            sz[tid] = sz[tid] * __expf(ma - mn) + sz[tid + s] * __expf(mb - mn);
            sm[tid] = mn;
        }
        __syncthreads();
    }
    M = sm[0];
    float invZ = 1.0f / sz[0];
    int t = blockIdx.x * 256 + tid;
    float pair = att_prev[t] + ((t > 0) ? att_prev[t - 1] : 0.f);
    float u = fmaxf(pair * __expf(ws[WS_SARR + t] - M) * invZ, 1e-6f);
    ws[WS_U + t] = u;
    float s = u;
    #pragma unroll
    for (int off = 32; off > 0; off >>= 1) s += __shfl_xor(s, off);
    int lane = tid & 63, wave = tid >> 6;
    if (lane == 0) wsum[wave] = s;
    __syncthreads();
    if (tid == 0) atomicAdd(&ws[WS_SSUM], wsum[0] + wsum[1] + wsum[2] + wsum[3]);
}

// ---------------- K3: w[t]=u/S -> out[512+t]; partial c into 32 replicas --------------
// 1024 blocks x 512 thr (full occupancy). Block covers 32 t's; 4 teams of 128, each
// team 8 t's across all 512 a's; LDS-combine teams; one team atomics into replica.
__global__ __launch_bounds__(512) void k3_context(
        const float* __restrict__ enc_h, float* __restrict__ ws,
        float* __restrict__ out) {
    __shared__ float cbuf[4 * 512];
    int tid = threadIdx.x;
    int team = tid >> 7, l = tid & 127;
    int a4 = 4 * l;
    int t0 = blockIdx.x * 32;
    float invS = 1.0f / ws[WS_SSUM];
    if (tid < 32) out[512 + t0 + tid] = ws[WS_U + t0 + tid] * invS;
    int tbase = t0 + team * 8;
    float4 acc = make_float4(0.f, 0.f, 0.f, 0.f);
    #pragma unroll
    for (int i = 0; i < 8; ++i) {
        int t = tbase + i;
        float wt = ws[WS_U + t] * invS;
        float4 e = *(const float4*)(enc_h + (size_t)t * ADIM + a4);
        acc.x = fmaf(wt, e.x, acc.x);
        acc.y = fmaf(wt, e.y, acc.y);
        acc.z = fmaf(wt, e.z, acc.z);
        acc.w = fmaf(wt, e.w, acc.w);
    }
    if (team != 0) *(float4*)&cbuf[team * 512 + a4] = acc;
    __syncthreads();
    if (team == 0) {
        float4 b1 = *(const float4*)&cbuf[1 * 512 + a4];
        float4 b2 = *(const float4*)&cbuf[2 * 512 + a4];
        float4 b3 = *(const float4*)&cbuf[3 * 512 + a4];
        float* rep = ws + WS_CREP + (blockIdx.x & 31) * 512;
        atomicAdd(&rep[a4 + 0], acc.x + b1.x + b2.x + b3.x);
        atomicAdd(&rep[a4 + 1], acc.y + b1.y + b2.y + b3.y);
        atomicAdd(&rep[a4 + 2], acc.z + b1.z + b2.z + b3.z);
        atomicAdd(&rep[a4 + 3], acc.w + b1.w + b2.w + b3.w);
    }
}

// ---------------- K4: c[a] = sum of 32 replicas -> out[0:512] -------------------------
__global__ __launch_bounds__(256) void k4_final(
        const float* __restrict__ ws, float* __restrict__ out) {
    int a = blockIdx.x * 256 + threadIdx.x;
    float acc = 0.f;
    #pragma unroll
    for (int r = 0; r < 32; ++r) acc += ws[WS_CREP + r * 512 + a];
    out[a] = acc;
}

extern "C" void kernel_launch(void* const* d_in, const int* in_sizes, int n_in,
                              void* d_out, int out_size, void* d_ws, size_t ws_size,
                              hipStream_t stream) {
    const float* dec_z    = (const float*)d_in[0];
    const float* att_prev = (const float*)d_in[1];
    const float* pre      = (const float*)d_in[2];
    const float* enc_h    = (const float*)d_in[3];
    const float* mask     = (const float*)d_in[4];
    const float* conv_w   = (const float*)d_in[5];
    const float* conv_b   = (const float*)d_in[6];
    const float* W_att    = (const float*)d_in[7];
    const float* W_dec    = (const float*)d_in[8];
    const float* W_g      = (const float*)d_in[9];
    const float* b_g      = (const float*)d_in[10];
    float* out = (float*)d_out;
    float* ws  = (float*)d_ws;

    k0_prep   <<<96,   256, 0, stream>>>(dec_z, conv_w, conv_b, W_att, W_dec, ws);
    k1_energy <<<512,  512, 0, stream>>>(att_prev, pre, mask, W_g, b_g, ws);
    k2_weights<<<128,  256, 0, stream>>>(att_prev, ws);
    k3_context<<<1024, 512, 0, stream>>>(enc_h, ws, out);
    k4_final  <<<2,    256, 0, stream>>>(ws, out);
}